// Round 4
// baseline (493.480 us; speedup 1.0000x reference)
//
#include <hip/hip_runtime.h>
#include <hip/hip_bf16.h>

typedef unsigned short u16;
typedef __bf16 bf16x8 __attribute__((ext_vector_type(8)));
typedef float f32x4 __attribute__((ext_vector_type(4)));

#define B_IMG 128
#define NOBJ  36
#define NNODE (B_IMG * NOBJ)

__device__ __forceinline__ float b2f(u16 u) {
    union { unsigned int i; float f; } v; v.i = ((unsigned int)u) << 16; return v.f;
}
__device__ __forceinline__ u16 f2b(float f) {
    union { float f; unsigned int i; } v; v.f = f;
    unsigned int u = v.i;
    return (u16)((u + 0x7fffu + ((u >> 16) & 1u)) >> 16);   // RNE
}

// ---------------------------------------------------------------------------
// fp32 -> bf16 packer. n4 = elems/4 (all our sizes divide by 4).
// ---------------------------------------------------------------------------
__global__ __launch_bounds__(256)
void conv_mat(const float* __restrict__ src, u16* __restrict__ dst, int n4) {
    const int i = blockIdx.x * 256 + threadIdx.x;
    if (i >= n4) return;
    const float4 f = ((const float4*)src)[i];
    ushort4 o; o.x = f2b(f.x); o.y = f2b(f.y); o.z = f2b(f.z); o.w = f2b(f.w);
    ((ushort4*)dst)[i] = o;
}

// ---------------------------------------------------------------------------
// fused fp32->bf16 convert + transpose: dst[c*R + r] = cvt(src[r*C + c]).
// dims multiples of 32.
// ---------------------------------------------------------------------------
__global__ __launch_bounds__(256)
void transpose_cvt(const float* __restrict__ src, u16* __restrict__ dst, int R, int C) {
    __shared__ u16 tile[32][33];
    const int bx = blockIdx.x * 32, by = blockIdx.y * 32;
    const int tx = threadIdx.x & 31, ty = threadIdx.x >> 5;   // 32x8
    #pragma unroll
    for (int i = ty; i < 32; i += 8)
        tile[i][tx] = f2b(src[(size_t)(by + i) * C + bx + tx]);
    __syncthreads();
    #pragma unroll
    for (int i = ty; i < 32; i += 8) dst[(size_t)(bx + i) * R + by + tx] = tile[tx][i];
}

// ---------------------------------------------------------------------------
// TN MFMA GEMM: C[M,N] = A[M,K] * Bt[N,K]^T   (bf16 in, fp32 acc)
// 128x128 tile, BK=32, 4 waves in 2x2, each wave 4x4 of 16x16x32 MFMA.
// EPI: 1 = splitK fp32 partial, 2 = +bias(fp32) then *qmul -> bf16, 0 = bf16.
// ---------------------------------------------------------------------------
template<int EPI>
__global__ __launch_bounds__(256)
void gemm_tn(const u16* __restrict__ A, const u16* __restrict__ Bt,
             int M, int N, int K, int kLen,
             float* __restrict__ Cf, u16* __restrict__ Cb,
             const float* __restrict__ bias, const float* __restrict__ qmul)
{
    __shared__ __align__(16) u16 lA[128 * 40];
    __shared__ __align__(16) u16 lB[128 * 40];

    const int t    = threadIdx.x;
    const int lane = t & 63;
    const int wave = t >> 6;
    const int wr = wave >> 1, wc = wave & 1;
    const int quad = lane >> 4, l16 = lane & 15;
    const int rowBase = blockIdx.y * 128;
    const int colBase = blockIdx.x * 128;
    const int k0 = blockIdx.z * kLen;

    const int row0 = t >> 2, col0 = t & 3;
    const int row1 = row0 + 64;

    const u16* pA0 = A  + (size_t)(rowBase + row0) * K + k0 + col0 * 8;
    const u16* pA1 = A  + (size_t)(rowBase + row1) * K + k0 + col0 * 8;
    const u16* pB0 = Bt + (size_t)(colBase + row0) * K + k0 + col0 * 8;
    const u16* pB1 = Bt + (size_t)(colBase + row1) * K + k0 + col0 * 8;

    const int soff0 = row0 * 40 + col0 * 8;
    const int soff1 = row1 * 40 + col0 * 8;

    int afr[4], bfr[4];
    #pragma unroll
    for (int r = 0; r < 4; r++) afr[r] = (wr * 64 + r * 16 + l16) * 40 + quad * 8;
    #pragma unroll
    for (int c = 0; c < 4; c++) bfr[c] = (wc * 64 + c * 16 + l16) * 40 + quad * 8;

    f32x4 acc[4][4];
    #pragma unroll
    for (int r = 0; r < 4; r++)
        #pragma unroll
        for (int c = 0; c < 4; c++)
            acc[r][c] = (f32x4){0.f, 0.f, 0.f, 0.f};

    uint4 ra0 = *(const uint4*)pA0;
    uint4 ra1 = *(const uint4*)pA1;
    uint4 rb0 = *(const uint4*)pB0;
    uint4 rb1 = *(const uint4*)pB1;

    for (int kk = 0; kk < kLen; kk += 32) {
        __syncthreads();
        *(uint4*)&lA[soff0] = ra0;
        *(uint4*)&lA[soff1] = ra1;
        *(uint4*)&lB[soff0] = rb0;
        *(uint4*)&lB[soff1] = rb1;
        __syncthreads();
        if (kk + 32 < kLen) {
            ra0 = *(const uint4*)(pA0 + kk + 32);
            ra1 = *(const uint4*)(pA1 + kk + 32);
            rb0 = *(const uint4*)(pB0 + kk + 32);
            rb1 = *(const uint4*)(pB1 + kk + 32);
        }
        bf16x8 avf[4], bvf[4];
        #pragma unroll
        for (int r = 0; r < 4; r++) avf[r] = *(const bf16x8*)&lA[afr[r]];
        #pragma unroll
        for (int c = 0; c < 4; c++) bvf[c] = *(const bf16x8*)&lB[bfr[c]];
        #pragma unroll
        for (int r = 0; r < 4; r++)
            #pragma unroll
            for (int c = 0; c < 4; c++)
                acc[r][c] = __builtin_amdgcn_mfma_f32_16x16x32_bf16(avf[r], bvf[c], acc[r][c], 0, 0, 0);
    }

    #pragma unroll
    for (int r = 0; r < 4; r++) {
        const int mBase = rowBase + wr * 64 + r * 16 + quad * 4;
        #pragma unroll
        for (int c = 0; c < 4; c++) {
            const int n = colBase + wc * 64 + c * 16 + l16;
            #pragma unroll
            for (int e = 0; e < 4; e++) {
                const int m = mBase + e;
                float v = acc[r][c][e];
                if (EPI == 1) {
                    Cf[((size_t)blockIdx.z * M + m) * N + n] = v;
                } else if (EPI == 2) {
                    v += bias[n];
                    v *= qmul[(size_t)(m / NOBJ) * N + n];
                    Cb[(size_t)m * N + n] = f2b(v);
                } else {
                    Cb[(size_t)m * N + n] = f2b(v);
                }
            }
        }
    }
}

// ---------------------------------------------------------------------------
__global__ __launch_bounds__(256)
void qcombine(const float* __restrict__ p, const float* __restrict__ bias,
              float* __restrict__ q, int MN, int S)
{
    const int i = blockIdx.x * 256 + threadIdx.x;
    float s = 0.f;
    for (int z = 0; z < S; z++) s += p[(size_t)z * MN + i];
    q[i] = s + bias[i & 2047];
}

// ---------------------------------------------------------------------------
// al_s / al_d: per (node, head) dot of h[n,hd,:] with a_src/a_dst (fp32 direct).
// ---------------------------------------------------------------------------
template<int H, int C>
__global__ __launch_bounds__(H * 64)
void al_kernel(const u16* __restrict__ h, const float* __restrict__ a_s,
               const float* __restrict__ a_d, float* __restrict__ als, float* __restrict__ ald)
{
    const int n = blockIdx.x;
    const int wv = threadIdx.x >> 6, lane = threadIdx.x & 63;
    constexpr int PL = C / 64;
    const u16*   hp  = h   + (size_t)n * (H * C) + wv * C + lane * PL;
    const float* asp = a_s + wv * C + lane * PL;
    const float* adp = a_d + wv * C + lane * PL;
    u16 hb[PL];
    if constexpr (PL == 4) { *(uint2*)hb = *(const uint2*)hp; }
    else                   { *(uint4*)hb = *(const uint4*)hp; }
    float s1 = 0.f, s2 = 0.f;
    #pragma unroll
    for (int i = 0; i < PL; i++) {
        const float hv = b2f(hb[i]);
        s1 += hv * asp[i];
        s2 += hv * adp[i];
    }
    #pragma unroll
    for (int off = 32; off > 0; off >>= 1) {
        s1 += __shfl_down(s1, off);
        s2 += __shfl_down(s2, off);
    }
    if (lane == 0) { als[n * H + wv] = s1; ald[n * H + wv] = s2; }
}

// ---------------------------------------------------------------------------
// Attention + aggregate per (image, head).  MODE 1: relu(agg+b) -> g (bf16)
//                                           MODE 2: relu(agg+b)+resid -> g
// ---------------------------------------------------------------------------
template<int H, int C, int MODE>
__global__ __launch_bounds__(256)
void attn_kernel(const u16* __restrict__ h, const float* __restrict__ als,
                 const float* __restrict__ ald, const float* __restrict__ bias,
                 const u16* __restrict__ resid, u16* __restrict__ outb)
{
    __shared__ __align__(16) u16 hl[36 * C];
    __shared__ float alpha[36 * 36];
    __shared__ float asl[36], adl[36];
    const int b = blockIdx.y, hd = blockIdx.x;
    const int t = threadIdx.x;
    const int nb = b * NOBJ;
    if (t < 36) { asl[t] = als[(nb + t) * H + hd]; adl[t] = ald[(nb + t) * H + hd]; }
    constexpr int CH = C / 8;
    for (int e = t; e < 36 * CH; e += 256) {
        const int row = e / CH, col = (e - row * CH) * 8;
        *(uint4*)&hl[row * C + col] = *(const uint4*)&h[(size_t)(nb + row) * (H * C) + hd * C + col];
    }
    __syncthreads();
    if (t < 36) {
        const float ad = adl[t];
        float mx = -1e30f;
        for (int s = 0; s < 36; s++) {
            float v = asl[s] + ad; v = (v > 0.f) ? v : 0.2f * v;
            alpha[t * 36 + s] = v; mx = fmaxf(mx, v);
        }
        float sum = 0.f;
        for (int s = 0; s < 36; s++) { const float ex = expf(alpha[t * 36 + s] - mx); alpha[t * 36 + s] = ex; sum += ex; }
        const float inv = 1.f / (sum + 1e-16f);
        for (int s = 0; s < 36; s++) alpha[t * 36 + s] *= inv;
    }
    __syncthreads();
    constexpr int NC4 = C / 4;
    for (int e = t; e < 36 * NC4; e += 256) {
        const int d = e / NC4, c4 = (e - d * NC4) * 4;
        float a0 = 0, a1 = 0, a2 = 0, a3 = 0;
        for (int s = 0; s < 36; s++) {
            const float al = alpha[d * 36 + s];
            const ushort4 hv = *(const ushort4*)&hl[s * C + c4];
            a0 += al * b2f(hv.x); a1 += al * b2f(hv.y); a2 += al * b2f(hv.z); a3 += al * b2f(hv.w);
        }
        const int n = nb + d;
        const size_t base = (size_t)n * (H * C) + hd * C + c4;
        const int bb = hd * C + c4;
        float v0 = a0 + bias[bb + 0];
        float v1 = a1 + bias[bb + 1];
        float v2 = a2 + bias[bb + 2];
        float v3 = a3 + bias[bb + 3];
        v0 = v0 > 0.f ? v0 : 0.f; v1 = v1 > 0.f ? v1 : 0.f;
        v2 = v2 > 0.f ? v2 : 0.f; v3 = v3 > 0.f ? v3 : 0.f;
        if (MODE == 2) {
            v0 += b2f(resid[base + 0]); v1 += b2f(resid[base + 1]);
            v2 += b2f(resid[base + 2]); v3 += b2f(resid[base + 3]);
        }
        outb[base + 0] = f2b(v0); outb[base + 1] = f2b(v1);
        outb[base + 2] = f2b(v2); outb[base + 3] = f2b(v3);
    }
}

// ---------------------------------------------------------------------------
// Layer-3 attention: 5 heads, C=512, mean over heads + b3 -> fp32 d_out.
// ---------------------------------------------------------------------------
__global__ __launch_bounds__(256)
void attn_mean_kernel(const u16* __restrict__ h, const float* __restrict__ als,
                      const float* __restrict__ ald, const float* __restrict__ b3,
                      float* __restrict__ outp)
{
    __shared__ __align__(16) u16 hl[36 * 256];
    __shared__ float alpha[36 * 36];
    __shared__ float asl[36], adl[36];
    __shared__ float oacc[36 * 256];
    const int b = blockIdx.y, ch = blockIdx.x;
    const int t = threadIdx.x;
    const int nb = b * NOBJ, cbase = ch * 256;
    for (int e = t; e < 36 * 256; e += 256) oacc[e] = 0.f;
    for (int hd = 0; hd < 5; hd++) {
        __syncthreads();
        if (t < 36) { asl[t] = als[(nb + t) * 5 + hd]; adl[t] = ald[(nb + t) * 5 + hd]; }
        for (int e = t; e < 36 * 32; e += 256) {
            const int row = e >> 5, col = (e & 31) * 8;
            *(uint4*)&hl[row * 256 + col] = *(const uint4*)&h[(size_t)(nb + row) * 2560 + hd * 512 + cbase + col];
        }
        __syncthreads();
        if (t < 36) {
            const float ad = adl[t];
            float mx = -1e30f;
            for (int s = 0; s < 36; s++) {
                float v = asl[s] + ad; v = (v > 0.f) ? v : 0.2f * v;
                alpha[t * 36 + s] = v; mx = fmaxf(mx, v);
            }
            float sum = 0.f;
            for (int s = 0; s < 36; s++) { const float ex = expf(alpha[t * 36 + s] - mx); alpha[t * 36 + s] = ex; sum += ex; }
            const float inv = 1.f / (sum + 1e-16f);
            for (int s = 0; s < 36; s++) alpha[t * 36 + s] *= inv;
        }
        __syncthreads();
        for (int e = t; e < 36 * 64; e += 256) {
            const int d = e >> 6, c4 = (e & 63) * 4;
            float a0 = 0, a1 = 0, a2 = 0, a3 = 0;
            for (int s = 0; s < 36; s++) {
                const float al = alpha[d * 36 + s];
                const ushort4 hv = *(const ushort4*)&hl[s * 256 + c4];
                a0 += al * b2f(hv.x); a1 += al * b2f(hv.y); a2 += al * b2f(hv.z); a3 += al * b2f(hv.w);
            }
            oacc[d * 256 + c4 + 0] += a0; oacc[d * 256 + c4 + 1] += a1;
            oacc[d * 256 + c4 + 2] += a2; oacc[d * 256 + c4 + 3] += a3;
        }
    }
    __syncthreads();
    for (int e = t; e < 36 * 64; e += 256) {
        const int d = e >> 6, c4 = (e & 63) * 4;
        #pragma unroll
        for (int j = 0; j < 4; j++)
            outp[(size_t)(nb + d) * 512 + cbase + c4 + j] =
                oacc[d * 256 + c4 + j] * 0.2f + b3[cbase + c4 + j];
    }
}

// ---------------------------------------------------------------------------
// All inputs fp32 (verified via round-3 dtype probe), output fp32.
// Workspace (62.1 MB, proven size in round 3):
//  E: qe_c 0.59M | of_c 18.87M
//  A: WqT -> (qpart @ +9.83M) -> x -> g1 -> h3        (23.59M)
//  B: WvT | q(@ +8.39M) -> W1T -> W2T -> g2           ( 9.44M)
//  C: h1 -> h2 -> W3T                                 ( 9.44M)
//  D: als, ald
// ---------------------------------------------------------------------------
extern "C" void kernel_launch(void* const* d_in, const int* in_sizes, int n_in,
                              void* d_out, int out_size, void* d_ws, size_t ws_size,
                              hipStream_t stream)
{
    const float* qe  = (const float*)d_in[0];    // [128,2400]
    const float* of  = (const float*)d_in[1];    // [4608,2048]
    const float* Wq  = (const float*)d_in[3];    // [2400,2048]
    const float* bq  = (const float*)d_in[4];
    const float* Wv  = (const float*)d_in[5];    // [2048,2048]
    const float* bv  = (const float*)d_in[6];
    const float* W1  = (const float*)d_in[7];    // [2048,1024]
    const float* a1s = (const float*)d_in[8];
    const float* a1d = (const float*)d_in[9];
    const float* b1  = (const float*)d_in[10];
    const float* W2  = (const float*)d_in[11];   // [1024,1024]
    const float* a2s = (const float*)d_in[12];
    const float* a2d = (const float*)d_in[13];
    const float* b2  = (const float*)d_in[14];
    const float* W3  = (const float*)d_in[15];   // [1024,2560]
    const float* a3s = (const float*)d_in[16];
    const float* a3d = (const float*)d_in[17];
    const float* b3  = (const float*)d_in[18];
    float* out = (float*)d_out;
    (void)ws_size; (void)in_sizes; (void)n_in; (void)out_size;

    char* W0 = (char*)d_ws;
    size_t off = 0;
    auto alloc = [&](size_t bytes) -> char* {
        char* p = W0 + off; off += (bytes + 255) & ~(size_t)255; return p;
    };
    u16* qe_c = (u16*)alloc(128ull * 2400 * 2);
    u16* of_c = (u16*)alloc(4608ull * 2048 * 2);
    const size_t szA = 4608ull * 2560 * 2;
    const size_t szB = 4608ull * 1024 * 2;
    const size_t szC = 4608ull * 1024 * 2;
    char* Abase = alloc(szA);
    char* Bbase = alloc(szB);
    char* Cbase = alloc(szC);
    char* Dbase = alloc((size_t)NNODE * 5 * 4 * 2);

    u16*   WqT   = (u16*)Abase;                           // S1-S2
    float* qpart = (float*)(Abase + 2048ull * 2400 * 2);  // S2-S3
    u16*   x     = (u16*)Abase;                           // S5-S7
    u16*   g1    = (u16*)Abase;                           // S9-S13
    u16*   h3    = (u16*)Abase;                           // S15-S17
    u16*   WvT   = (u16*)Bbase;                           // S4-S5
    float* q     = (float*)(Bbase + 2048ull * 2048 * 2);  // S3-S5
    u16*   W1T   = (u16*)Bbase;                           // S6-S7
    u16*   W2T   = (u16*)Bbase;                           // S10-S11
    u16*   g2    = (u16*)Bbase;                           // S13-S15
    u16*   h1    = (u16*)Cbase;                           // S7-S9
    u16*   h2    = (u16*)Cbase;                           // S11-S13
    u16*   W3T   = (u16*)Cbase;                           // S14-S15
    float* als   = (float*)Dbase;
    float* ald   = (float*)(Dbase + (size_t)NNODE * 5 * 4);

    // S0: canonicalize activations to bf16
    conv_mat<<<(128 * 2400 / 4 + 255) / 256, 256, 0, stream>>>(qe, qe_c, 128 * 2400 / 4);
    conv_mat<<<(4608 * 2048 / 4 + 255) / 256, 256, 0, stream>>>(of, of_c, 4608 * 2048 / 4);

    // S1-S3: q = qe @ Wq + bq   (splitK=5, fp32 result)
    transpose_cvt<<<dim3(64, 75), 256, 0, stream>>>(Wq, WqT, 2400, 2048);
    gemm_tn<1><<<dim3(16, 1, 5), 256, 0, stream>>>(qe_c, WqT, 128, 2048, 2400, 480,
                                                   qpart, nullptr, nullptr, nullptr);
    qcombine<<<dim3(128 * 2048 / 256), 256, 0, stream>>>(qpart, bq, q, 128 * 2048, 5);

    // S4-S5: x = (of @ Wv + bv) * q_rep
    transpose_cvt<<<dim3(64, 64), 256, 0, stream>>>(Wv, WvT, 2048, 2048);
    gemm_tn<2><<<dim3(16, 36, 1), 256, 0, stream>>>(of_c, WvT, 4608, 2048, 2048, 2048,
                                                    nullptr, x, bv, q);

    // S6-S9: layer 1
    transpose_cvt<<<dim3(32, 64), 256, 0, stream>>>(W1, W1T, 2048, 1024);
    gemm_tn<0><<<dim3(8, 36, 1), 256, 0, stream>>>(x, W1T, 4608, 1024, 2048, 2048,
                                                   nullptr, h1, nullptr, nullptr);
    al_kernel<4, 256><<<dim3(NNODE), 256, 0, stream>>>(h1, a1s, a1d, als, ald);
    attn_kernel<4, 256, 1><<<dim3(4, B_IMG), 256, 0, stream>>>(h1, als, ald, b1, nullptr, g1);

    // S10-S13: layer 2 (+ residual g1)
    transpose_cvt<<<dim3(32, 32), 256, 0, stream>>>(W2, W2T, 1024, 1024);
    gemm_tn<0><<<dim3(8, 36, 1), 256, 0, stream>>>(g1, W2T, 4608, 1024, 1024, 1024,
                                                   nullptr, h2, nullptr, nullptr);
    al_kernel<4, 256><<<dim3(NNODE), 256, 0, stream>>>(h2, a2s, a2d, als, ald);
    attn_kernel<4, 256, 2><<<dim3(4, B_IMG), 256, 0, stream>>>(h2, als, ald, b2, g1, g2);

    // S14-S17: layer 3 (5 heads, mean + b3) -> fp32 out
    transpose_cvt<<<dim3(80, 32), 256, 0, stream>>>(W3, W3T, 1024, 2560);
    gemm_tn<0><<<dim3(20, 36, 1), 256, 0, stream>>>(g2, W3T, 4608, 2560, 1024, 1024,
                                                    nullptr, h3, nullptr, nullptr);
    al_kernel<5, 512><<<dim3(NNODE), 320, 0, stream>>>(h3, a3s, a3d, als, ald);
    attn_mean_kernel<<<dim3(2, B_IMG), 256, 0, stream>>>(h3, als, ald, b3, out);
}